// Round 8
// baseline (2226.704 us; speedup 1.0000x reference)
//
#include <hip/hip_runtime.h>
#include <hip/hip_bf16.h>
#include <stdint.h>

#define N_NODES  50000
#define N_EDGES  800000
#define N_GRAPHS 512

#define BINSZ   64
#define NBIN    ((N_NODES + BINSZ - 1)/BINSZ)    // 782
#define MAXB    1792                             // per-bin cap (mean 1024 + 24 sigma)
#define NBKT    98                               // src>>9 buckets (50000/512)
#define NSCAT   512
#define SCHUNK  ((N_EDGES + NSCAT - 1)/NSCAT)    // 1563
#define NCAST   1563                             // cast blocks @1024 thr
#define NWPREP  97                               // weight-prep blocks @1024 thr

typedef __attribute__((ext_vector_type(8))) short  short8;
typedef __attribute__((ext_vector_type(4))) float  floatx4;
typedef unsigned short u16;
typedef unsigned int   u32;

__device__ __forceinline__ u16 f2b(float f){
  u32 u = __float_as_uint(f);
  u = (u + 0x7FFFu + ((u >> 16) & 1u)) >> 16;   // RNE
  return (u16)u;
}
__device__ __forceinline__ u32 pack2(float a, float b){
  return (u32)f2b(a) | ((u32)f2b(b) << 16);
}
__device__ __forceinline__ float blo(u32 v){ return __uint_as_float(v << 16); }
__device__ __forceinline__ float bhi(u32 v){ return __uint_as_float(v & 0xFFFF0000u); }
__device__ __forceinline__ float b2f(u16 s){ return __uint_as_float(((u32)s) << 16); }

// ---- scatter (bin by dst>>6) + X cast + weight-prep/bounds ------------------
__launch_bounds__(1024)
__global__ void k_scatter(const int* __restrict__ src, const int* __restrict__ dst,
                          int* __restrict__ bincur, u32* __restrict__ rec,
                          const float4* __restrict__ x, uint2* __restrict__ X1,
                          const float* __restrict__ Wrel1, const float* __restrict__ Wroot1,
                          const float* __restrict__ Wrel2, const float* __restrict__ Wroot2,
                          u16* __restrict__ wcat,
                          const float* __restrict__ W1, const float* __restrict__ W2,
                          u16* __restrict__ wm,
                          const int* __restrict__ batch, int* __restrict__ start){
  __shared__ int h[NBIN];
  __shared__ int gadj[NBIN];
  __shared__ int cursor[NBIN];
  __shared__ int wsum[13];
  __shared__ u32 st[SCHUNK];
  int blk = blockIdx.x, t = threadIdx.x;
  if (blk >= NSCAT + NCAST){
    int id = (blk - NSCAT - NCAST)*1024 + t;
    if (id < 65536){
      int l = id >> 15;
      int r = id & 32767;
      int n = r >> 8;
      int k = r & 255;
      const float* Wrel  = l ? Wrel2  : Wrel1;
      const float* Wroot = l ? Wroot2 : Wroot1;
      float w = (k < 128) ? Wrel[k*128 + n] : Wroot[(k-128)*128 + n];
      int c = k >> 3, j = k & 7;
      wcat[l*32768 + n*256 + ((c ^ (n & 15)) << 3) + j] = f2b(w);
    } else if (id < 98304){
      int id2 = id - 65536;
      int l = id2 >> 14;
      int r = id2 & 16383;
      int n = r >> 7;
      int k = r & 127;
      const float* W = l ? W2 : W1;
      wm[l*16384 + n*128 + k] = f2b(W[k*128 + n]);
    } else {
      int g = id - 98304;
      if (g <= N_GRAPHS){
        int lo = 0, hi = N_NODES;
        while (lo < hi){ int mid = (lo + hi) >> 1; if (batch[mid] < g) lo = mid + 1; else hi = mid; }
        start[g] = lo;
      }
    }
    return;
  }
  if (blk >= NSCAT){
    int i = (blk - NSCAT)*1024 + t;
    if (i < 1600000){
      float4 v = x[i];
      X1[i] = make_uint2(pack2(v.x, v.y), pack2(v.z, v.w));
    }
    return;
  }
  int base = blk*SCHUNK;
  int end  = min(base + SCHUNK, N_EDGES);
  int cnt  = end - base;
  for (int i = t; i < NBIN; i += 1024) h[i] = 0;
  __syncthreads();
  u32 r[2]; int nb[2]; int ne = 0;
  for (int i = base + t; i < end; i += 1024){
    int d = dst[i], s = src[i];
    r[ne]  = ((u32)d << 16) | (u32)s;     // dst<50000, src<65536 -> fits u32
    nb[ne] = d >> 6;
    atomicAdd(&h[nb[ne]], 1);
    ne++;
  }
  __syncthreads();
  int hv = 0, incl = 0;
  if (t < NBIN){
    hv = h[t];
    incl = hv;
    int lane = t & 63;
    #pragma unroll
    for (int off = 1; off < 64; off <<= 1){
      int n = __shfl_up(incl, off);
      if (lane >= off) incl += n;
    }
    if (lane == 63 || t == NBIN-1) wsum[t >> 6] = incl;
  }
  __syncthreads();
  if (t < NBIN){
    int g = t >> 6;
    int pre = 0;
    for (int gg = 0; gg < g; gg++) pre += wsum[gg];
    int o = pre + incl - hv;                 // exclusive offset of bin t
    cursor[t] = o;
    int gb = t*MAXB + (hv ? atomicAdd(&bincur[t], hv) : 0);
    gadj[t] = gb - o;
  }
  __syncthreads();
  for (int j = 0; j < ne; j++){
    int p = atomicAdd(&cursor[nb[j]], 1);
    st[p] = r[j];
  }
  __syncthreads();
  for (int i = t; i < cnt; i += 1024){
    u32 v = st[i];
    rec[gadj[v >> 22] + i] = v;              // v>>22 == dst>>6 == bin
  }
}

// ---- LDS-atomic aggregation core: block owns 64 dst nodes -------------------
// srt entries: src<<6 | ldst, walked in src-ascending (bucketed) order.
// acc[64][128] f32 in LDS; 8-deep load pipeline per wave; waves co-located.
__device__ __forceinline__ void agg_from_srt(const u32* __restrict__ X32,
    const u32* srt, int n, float* acc, int t){
  int w = t >> 6, ln = t & 63;
  for (int i = w*8; i < n; i += 64){
    int m = min(8, n - i);
    u32 rr[8]; u32 vv[8];
    #pragma unroll
    for (int e = 0; e < 8; e++) rr[e] = (e < m) ? srt[i + e] : 0u;
    #pragma unroll
    for (int e = 0; e < 8; e++) if (e < m) vv[e] = X32[(rr[e] >> 6)*64 + ln];
    #pragma unroll
    for (int e = 0; e < 8; e++) if (e < m){
      float* p = acc + (rr[e] & 63)*128 + 2*ln;
      atomicAdd(p,     blo(vv[e]));
      atomicAdd(p + 1, bhi(vv[e]));
    }
  }
}

// ---- pass 1: bucket-by-src + deg/dinv + persist edge list + aggregate -------
__launch_bounds__(512)
__global__ void k_binagg1(const u32* __restrict__ rec, const int* __restrict__ bincur,
                          u32* __restrict__ edgeS, float* __restrict__ dinv,
                          const u16* __restrict__ X, u16* __restrict__ M){
  __shared__ u32 recs[MAXB];
  __shared__ u32 srt[MAXB];
  __shared__ float acc[BINSZ*128];
  __shared__ int hist[NBKT];
  __shared__ int cur[NBKT];
  __shared__ int deg[BINSZ];
  __shared__ int ws2[2];
  int b = blockIdx.x, t = threadIdx.x;
  int s0 = b*MAXB;
  int n = bincur[b];
  for (int i = t; i < BINSZ*128; i += 512) acc[i] = 0.f;
  if (t < NBKT) hist[t] = 0;
  if (t < BINSZ) deg[t] = 0;
  for (int i = t; i < n; i += 512) recs[i] = rec[s0 + i];
  __syncthreads();
  for (int i = t; i < n; i += 512){
    u32 v = recs[i];
    atomicAdd(&hist[(v & 0xFFFFu) >> 9], 1);
    atomicAdd(&deg[(v >> 16) & 63], 1);
  }
  __syncthreads();
  int hv = 0, incl = 0;
  if (t < NBKT){
    hv = hist[t];
    incl = hv;
    int lane = t & 63;
    #pragma unroll
    for (int off = 1; off < 64; off <<= 1){
      int nn = __shfl_up(incl, off);
      if (lane >= off) incl += nn;
    }
    if (lane == 63 || t == NBKT-1) ws2[t >> 6] = incl;
  }
  __syncthreads();
  if (t < NBKT){
    int pre = (t >= 64) ? ws2[0] : 0;
    cur[t] = pre + incl - hv;
  }
  __syncthreads();
  for (int i = t; i < n; i += 512){
    u32 v = recs[i];
    int p = atomicAdd(&cur[(v & 0xFFFFu) >> 9], 1);
    srt[p] = ((v & 0xFFFFu) << 6) | ((v >> 16) & 63);
  }
  __syncthreads();
  for (int i = t; i < n; i += 512) edgeS[s0 + i] = srt[i];
  if (t < BINSZ){
    int node = b*BINSZ + t;
    if (node < N_NODES) dinv[node] = 1.0f / (float)max(deg[t], 1);
  }
  agg_from_srt((const u32*)X, srt, n, acc, t);
  __syncthreads();
  for (int i = t; i < BINSZ*64; i += 512){
    int nd = i >> 6, cp = i & 63;
    int node = b*BINSZ + nd;
    if (node < N_NODES){
      float di = 1.0f / (float)max(deg[nd], 1);
      ((u32*)M)[node*64 + cp] = pack2(acc[nd*128 + 2*cp]*di, acc[nd*128 + 2*cp + 1]*di);
    }
  }
}

// ---- passes 2,3: read persisted bucketed edge list, aggregate ---------------
__launch_bounds__(512)
__global__ void k_binagg2(const u32* __restrict__ edgeS, const int* __restrict__ bincur,
                          const float* __restrict__ dinv,
                          const u16* __restrict__ X, u16* __restrict__ M){
  __shared__ u32 srt[MAXB];
  __shared__ float acc[BINSZ*128];
  __shared__ float sdi[BINSZ];
  int b = blockIdx.x, t = threadIdx.x;
  int s0 = b*MAXB;
  int n = bincur[b];
  for (int i = t; i < BINSZ*128; i += 512) acc[i] = 0.f;
  for (int i = t; i < n; i += 512) srt[i] = edgeS[s0 + i];
  if (t < BINSZ){
    int node = b*BINSZ + t;
    sdi[t] = (node < N_NODES) ? dinv[node] : 0.f;
  }
  __syncthreads();
  agg_from_srt((const u32*)X, srt, n, acc, t);
  __syncthreads();
  for (int i = t; i < BINSZ*64; i += 512){
    int nd = i >> 6, cp = i & 63;
    int node = b*BINSZ + nd;
    if (node < N_NODES){
      float di = sdi[nd];
      ((u32*)M)[node*64 + cp] = pack2(acc[nd*128 + 2*cp]*di, acc[nd*128 + 2*cp + 1]*di);
    }
  }
}

// ---- GEMM: Xout = relu([M|X] @ Wcat + brel)  (M=50000, K=256, N=128) ------
__launch_bounds__(256, 2)
__global__ void k_gemm2(const u16* __restrict__ M, const u16* __restrict__ X,
                        const u16* __restrict__ Wcat, const float* __restrict__ brel,
                        u16* __restrict__ Xout){
  __shared__ u16 Bs[128*256];
  {
    const uint4* s = (const uint4*)Wcat;
    uint4* d = (uint4*)Bs;
    #pragma unroll
    for (int i = 0; i < 16; i++) d[threadIdx.x + 256*i] = s[threadIdx.x + 256*i];
  }
  __syncthreads();

  int wave = threadIdx.x >> 6, lane = threadIdx.x & 63;
  int l15 = lane & 15, quad = lane >> 4;
  int wy = wave >> 1, wx = wave & 1;
  int rowBase = blockIdx.x*128 + wy*64;

  floatx4 acc[4][4] = {};

  #pragma unroll
  for (int k0 = 0; k0 < 256; k0 += 32){
    const u16* Asrc = (k0 < 128) ? M : X;
    int kk = k0 & 127;
    int c = (k0 >> 3) + quad;
    short8 a[4];
    #pragma unroll
    for (int mt = 0; mt < 4; mt++){
      int row = rowBase + mt*16 + l15;
      if (row > N_NODES-1) row = N_NODES-1;   // clamp; stores are masked
      a[mt] = *(const short8*)(Asrc + row*128 + kk + quad*8);
    }
    #pragma unroll
    for (int nt = 0; nt < 4; nt++){
      int n = wx*64 + nt*16 + l15;
      short8 b = *(const short8*)(Bs + n*256 + ((c ^ (n & 15)) << 3));
      #pragma unroll
      for (int mt = 0; mt < 4; mt++)
        acc[mt][nt] = __builtin_amdgcn_mfma_f32_16x16x32_bf16(a[mt], b, acc[mt][nt], 0, 0, 0);
    }
  }

  float bc[4];
  #pragma unroll
  for (int nt = 0; nt < 4; nt++) bc[nt] = brel[wx*64 + nt*16 + l15];

  #pragma unroll
  for (int mt = 0; mt < 4; mt++){
    int rbase = rowBase + mt*16 + quad*4;
    #pragma unroll
    for (int r = 0; r < 4; r++){
      int row = rbase + r;
      if (row < N_NODES){
        #pragma unroll
        for (int nt = 0; nt < 4; nt++){
          int n = wx*64 + nt*16 + l15;
          Xout[row*128 + n] = f2b(fmaxf(acc[mt][nt][r] + bc[nt], 0.f));
        }
      }
    }
  }
}

// ---- streaming pool + conv3: Gb[g] = pool(M3)@Wrel3 + pool(X3)@Wroot3 + brel3
__launch_bounds__(256)
__global__ void k_poolconv(const u16* __restrict__ M3, const u16* __restrict__ X3,
                           const int* __restrict__ start,
                           const float* __restrict__ Wrel, const float* __restrict__ Wroot,
                           const float* __restrict__ brel, u16* __restrict__ Gb){
  __shared__ float2 pm[4][64], px[4][64];
  __shared__ float pmS[128], pxS[128], part[256];
  int gid = blockIdx.x;
  int wave = threadIdx.x >> 6, lane = threadIdx.x & 63;
  int s = start[gid], e = start[gid+1];
  const u32* Mu = (const u32*)M3;
  const u32* Xu = (const u32*)X3;
  float m0 = 0.f, m1 = 0.f, x0 = 0.f, x1 = 0.f;
  for (int i = s + wave; i < e; i += 4){
    u32 vm = Mu[i*64 + lane];
    u32 vx = Xu[i*64 + lane];
    m0 += blo(vm); m1 += bhi(vm);
    x0 += blo(vx); x1 += bhi(vx);
  }
  pm[wave][lane] = make_float2(m0, m1);
  px[wave][lane] = make_float2(x0, x1);
  __syncthreads();
  if (wave == 0){
    float inv = 1.0f / (float)max(e - s, 1);
    float2 a0 = pm[0][lane], a1 = pm[1][lane], a2 = pm[2][lane], a3 = pm[3][lane];
    float2 b0 = px[0][lane], b1 = px[1][lane], b2 = px[2][lane], b3 = px[3][lane];
    pmS[2*lane]   = ((a0.x+a1.x)+(a2.x+a3.x))*inv;
    pmS[2*lane+1] = ((a0.y+a1.y)+(a2.y+a3.y))*inv;
    pxS[2*lane]   = ((b0.x+b1.x)+(b2.x+b3.x))*inv;
    pxS[2*lane+1] = ((b0.y+b1.y)+(b2.y+b3.y))*inv;
  }
  __syncthreads();
  int t = threadIdx.x;
  int n = t & 127, half = t >> 7;
  const float* W = half ? Wroot : Wrel;
  const float* S = half ? pxS : pmS;
  float a = 0.f;
  for (int k = 0; k < 128; k++) a = fmaf(S[k], W[k*128 + n], a);
  part[t] = a;
  __syncthreads();
  if (t < 128) Gb[gid*128 + t] = f2b(part[t] + part[t + 128] + brel[t]);
}

// ---- fused MLP (8 blocks x 64 rows) ----------------------------------------
#define APAD 136
__launch_bounds__(256)
__global__ void k_mlp(const u16* __restrict__ Gb, const u16* __restrict__ wm,
                      const float* __restrict__ b1, const float* __restrict__ b2,
                      const float* __restrict__ Wo, const float* __restrict__ bo,
                      float* __restrict__ out){
  __shared__ u16 Apad[64*APAD];
  int t = threadIdx.x;
  int wave = t >> 6, lane = t & 63;
  int l15 = lane & 15, quad = lane >> 4;
  int R = blockIdx.x*64;

  floatx4 acc[8] = {};
  #pragma unroll
  for (int k0 = 0; k0 < 128; k0 += 32){
    int row = R + wave*16 + l15;
    short8 a = *(const short8*)(Gb + row*128 + k0 + quad*8);
    #pragma unroll
    for (int nt = 0; nt < 8; nt++){
      short8 b = *(const short8*)(wm + (nt*16 + l15)*128 + k0 + quad*8);
      acc[nt] = __builtin_amdgcn_mfma_f32_16x16x32_bf16(a, b, acc[nt], 0, 0, 0);
    }
  }
  #pragma unroll
  for (int nt = 0; nt < 8; nt++){
    int coln = nt*16 + l15;
    float bc = b1[coln];
    int lmb = wave*16 + quad*4;
    #pragma unroll
    for (int r = 0; r < 4; r++)
      Apad[(lmb + r)*APAD + coln] = f2b(fmaxf(acc[nt][r] + bc, 0.f));
  }
  __syncthreads();

  floatx4 acc2[8] = {};
  #pragma unroll
  for (int k0 = 0; k0 < 128; k0 += 32){
    short8 a = *(const short8*)(Apad + (wave*16 + l15)*APAD + k0 + quad*8);
    #pragma unroll
    for (int nt = 0; nt < 8; nt++){
      short8 b = *(const short8*)(wm + 16384 + (nt*16 + l15)*128 + k0 + quad*8);
      acc2[nt] = __builtin_amdgcn_mfma_f32_16x16x32_bf16(a, b, acc2[nt], 0, 0, 0);
    }
  }
  __syncthreads();
  #pragma unroll
  for (int nt = 0; nt < 8; nt++){
    int coln = nt*16 + l15;
    float bc = b2[coln];
    int lmb = wave*16 + quad*4;
    #pragma unroll
    for (int r = 0; r < 4; r++)
      Apad[(lmb + r)*APAD + coln] = f2b(fmaxf(acc2[nt][r] + bc, 0.f));
  }
  __syncthreads();

  if (t < 128){
    int row = t >> 1;
    int c0  = (t & 1)*4;
    float o0 = bo[c0], o1 = bo[c0+1], o2 = bo[c0+2], o3 = bo[c0+3];
    for (int k = 0; k < 128; k++){
      float h = b2f(Apad[row*APAD + k]);
      const float* w = Wo + k*8 + c0;
      o0 = fmaf(h, w[0], o0); o1 = fmaf(h, w[1], o1);
      o2 = fmaf(h, w[2], o2); o3 = fmaf(h, w[3], o3);
    }
    float* op = out + (R + row)*8 + c0;
    op[0] = o0; op[1] = o1; op[2] = o2; op[3] = o3;
  }
}

extern "C" void kernel_launch(void* const* d_in, const int* in_sizes, int n_in,
                              void* d_out, int out_size, void* d_ws, size_t ws_size,
                              hipStream_t stream){
  const float* x     = (const float*)d_in[0];
  const int*   ei    = (const int*)d_in[1];
  const int*   batch = (const int*)d_in[2];
  const float* Wrel1 = (const float*)d_in[3];
  const float* brel1 = (const float*)d_in[4];
  const float* Wroot1= (const float*)d_in[5];
  const float* Wrel2 = (const float*)d_in[6];
  const float* brel2 = (const float*)d_in[7];
  const float* Wroot2= (const float*)d_in[8];
  const float* Wrel3 = (const float*)d_in[9];
  const float* brel3 = (const float*)d_in[10];
  const float* Wroot3= (const float*)d_in[11];
  const float* W1 = (const float*)d_in[12]; const float* b1 = (const float*)d_in[13];
  const float* W2 = (const float*)d_in[14]; const float* b2 = (const float*)d_in[15];
  const float* Wo = (const float*)d_in[16]; const float* bo = (const float*)d_in[17];
  const int* esrc = ei;
  const int* edst = ei + N_EDGES;

  char* ws = (char*)d_ws;
  size_t off = 0;
  auto alloc = [&](size_t bytes)->char*{
    char* p = ws + off; off += (bytes + 255) & ~(size_t)255; return p;
  };
  u16*   X1     = (u16*)  alloc((size_t)N_NODES*128*2);
  u16*   X2     = (u16*)  alloc((size_t)N_NODES*128*2);
  u16*   X3     = (u16*)  alloc((size_t)N_NODES*128*2);
  u16*   Mb     = (u16*)  alloc((size_t)N_NODES*128*2);
  u16*   wcat   = (u16*)  alloc((size_t)2*128*256*2);
  u16*   wm     = (u16*)  alloc((size_t)2*128*128*2);
  u16*   Gb     = (u16*)  alloc((size_t)N_GRAPHS*128*2);
  u32*   rec    = (u32*)  alloc((size_t)NBIN*MAXB*4);
  u32*   edgeS  = (u32*)  alloc((size_t)NBIN*MAXB*4);
  float* dinv   = (float*)alloc((size_t)(NBIN*BINSZ)*4);
  int*   start  = (int*)  alloc((size_t)(N_GRAPHS+1)*4);
  int*   bincur = (int*)  alloc((size_t)NBIN*4);

  dim3 b256(256);
  hipMemsetAsync(bincur, 0, (size_t)NBIN*4, stream);
  k_scatter<<<NSCAT + NCAST + NWPREP, dim3(1024), 0, stream>>>(
      esrc, edst, bincur, rec, (const float4*)x, (uint2*)X1,
      Wrel1, Wroot1, Wrel2, Wroot2, wcat, W1, W2, wm, batch, start);

  const int ggrid = (N_NODES + 127)/128;   // 391

  k_binagg1<<<NBIN, dim3(512), 0, stream>>>(rec, bincur, edgeS, dinv, X1, Mb);
  k_gemm2  <<<ggrid, b256, 0, stream>>>(Mb, X1, wcat + 0*32768, brel1, X2);

  k_binagg2<<<NBIN, dim3(512), 0, stream>>>(edgeS, bincur, dinv, X2, Mb);
  k_gemm2  <<<ggrid, b256, 0, stream>>>(Mb, X2, wcat + 1*32768, brel2, X3);

  k_binagg2<<<NBIN, dim3(512), 0, stream>>>(edgeS, bincur, dinv, X3, Mb);
  k_poolconv<<<N_GRAPHS, b256, 0, stream>>>(Mb, X3, start, Wrel3, Wroot3, brel3, Gb);
  k_mlp    <<<8, b256, 0, stream>>>(Gb, wm, b1, b2, Wo, bo, (float*)d_out);
}

// Round 9
// 253.422 us; speedup vs baseline: 8.7866x; 8.7866x over previous
//
#include <hip/hip_runtime.h>
#include <hip/hip_bf16.h>
#include <stdint.h>

#define N_NODES  50000
#define N_EDGES  800000
#define N_GRAPHS 512

#define BINSZ   128
#define NBIN    ((N_NODES + BINSZ - 1)/BINSZ)    // 391
#define MAXBIN  3072
#define NSCAT   256
#define SCHUNK  ((N_EDGES + NSCAT - 1)/NSCAT)    // 3125

typedef __attribute__((ext_vector_type(8))) short  short8;
typedef __attribute__((ext_vector_type(4))) float  floatx4;
typedef unsigned short u16;
typedef unsigned int   u32;

__device__ __forceinline__ u16 f2b(float f){
  u32 u = __float_as_uint(f);
  u = (u + 0x7FFFu + ((u >> 16) & 1u)) >> 16;   // RNE
  return (u16)u;
}
__device__ __forceinline__ u32 pack2(float a, float b){
  return (u32)f2b(a) | ((u32)f2b(b) << 16);
}
__device__ __forceinline__ float blo(u32 v){ return __uint_as_float(v << 16); }
__device__ __forceinline__ float bhi(u32 v){ return __uint_as_float(v & 0xFFFF0000u); }
__device__ __forceinline__ float b2f(u16 s){ return __uint_as_float(((u32)s) << 16); }

// gather-accumulate one node's neighbor rows (bf16 X, 128ch).
// half-waves (sub 0/1) process alternate edges; lane ln holds ch[4ln..4ln+3].
// 8-edge unroll keeps 4 independent row-loads in flight per half-wave.
__device__ __forceinline__ floatx4 gather_node(const uint2* __restrict__ Xu,
    const int* __restrict__ col, u32 r, int lane, int sub, int ln, int* degOut){
  int cs = (int)(r >> 11), d = (int)(r & 2047), ce = cs + d;
  float a0 = 0.f, a1 = 0.f, a2 = 0.f, a3 = 0.f;
  for (int cb = cs; cb < ce; cb += 64){
    int cnt = min(64, ce - cb);
    int idx = 0;
    if (cb + lane < ce) idx = col[cb + lane];
    int k = 0;
    for (; k + 8 <= cnt; k += 8){
      int jA = __shfl(idx, k + sub);
      int jB = __shfl(idx, k + 2 + sub);
      int jC = __shfl(idx, k + 4 + sub);
      int jD = __shfl(idx, k + 6 + sub);
      uint2 vA = Xu[jA*32 + ln];
      uint2 vB = Xu[jB*32 + ln];
      uint2 vC = Xu[jC*32 + ln];
      uint2 vD = Xu[jD*32 + ln];
      a0 += (blo(vA.x) + blo(vB.x)) + (blo(vC.x) + blo(vD.x));
      a1 += (bhi(vA.x) + bhi(vB.x)) + (bhi(vC.x) + bhi(vD.x));
      a2 += (blo(vA.y) + blo(vB.y)) + (blo(vC.y) + blo(vD.y));
      a3 += (bhi(vA.y) + bhi(vB.y)) + (bhi(vC.y) + bhi(vD.y));
    }
    for (; k + 2 <= cnt; k += 2){
      int j = __shfl(idx, k + sub);
      uint2 v = Xu[j*32 + ln];
      a0 += blo(v.x); a1 += bhi(v.x); a2 += blo(v.y); a3 += bhi(v.y);
    }
    if (k < cnt){
      int j = __shfl(idx, k);
      if (sub == 0){
        uint2 v = Xu[j*32 + ln];
        a0 += blo(v.x); a1 += bhi(v.x); a2 += blo(v.y); a3 += bhi(v.y);
      }
    }
  }
  a0 += __shfl_xor(a0, 32); a1 += __shfl_xor(a1, 32);
  a2 += __shfl_xor(a2, 32); a3 += __shfl_xor(a3, 32);
  *degOut = d;
  floatx4 out = {a0, a1, a2, a3};
  return out;
}

// ---- coalesced scatter: register-staged, locally bin-sorted ----------------
// rec packs dst<<16 | src (both < 65536). Writes are position-ordered ->
// runs of ~8 consecutive records per bin -> coalesced bursts.
__launch_bounds__(1024)
__global__ void k_scatter(const int* __restrict__ src, const int* __restrict__ dst,
                          int* __restrict__ bincur, u32* __restrict__ rec){
  __shared__ int h[NBIN];
  __shared__ int gadj[NBIN];
  __shared__ int cursor[NBIN];
  __shared__ int wsum[8];
  __shared__ u32 st[SCHUNK];
  int t = threadIdx.x;
  int base = blockIdx.x*SCHUNK;
  int end  = min(base + SCHUNK, N_EDGES);
  int cnt  = end - base;
  for (int i = t; i < NBIN; i += 1024) h[i] = 0;
  __syncthreads();
  u32 r[4]; int nb[4]; int ne = 0;
  for (int i = base + t; i < end; i += 1024){
    int d = dst[i], s = src[i];
    r[ne]  = ((u32)d << 16) | (u32)s;
    nb[ne] = d >> 7;
    atomicAdd(&h[nb[ne]], 1);
    ne++;
  }
  __syncthreads();
  // block-level exclusive scan over 391 bins (shfl within 64-lane waves)
  int hv = 0, incl = 0;
  if (t < NBIN){
    hv = h[t];
    incl = hv;
    int lane = t & 63;
    #pragma unroll
    for (int off = 1; off < 64; off <<= 1){
      int n = __shfl_up(incl, off);
      if (lane >= off) incl += n;
    }
    if (lane == 63 || t == NBIN-1) wsum[t >> 6] = incl;
  }
  __syncthreads();
  if (t < NBIN){
    int g = t >> 6;
    int pre = 0;
    for (int gg = 0; gg < g; gg++) pre += wsum[gg];
    int o = pre + incl - hv;                 // exclusive offset of bin t
    cursor[t] = o;
    int gb = t*MAXBIN + (hv ? atomicAdd(&bincur[t], hv) : 0);
    gadj[t] = gb - o;
  }
  __syncthreads();
  for (int j = 0; j < ne; j++){
    int p = atomicAdd(&cursor[nb[j]], 1);
    st[p] = r[j];
  }
  __syncthreads();
  for (int i = t; i < cnt; i += 1024){
    u32 v = st[i];
    rec[gadj[v >> 23] + i] = v;              // v>>23 == dst>>7 == bin
  }
}

// ---- CSR step 2 (391 blocks) fused with cast/weight-prep/bounds ------------
#define C_BIN   NBIN
#define C_CAST  (C_BIN + 6250)
#define C_W2    (C_CAST + 256)
#define C_MLP   (C_W2 + 128)
#define C_BND   (C_MLP + 3)
__launch_bounds__(256)
__global__ void k_csrprep(const u32* __restrict__ rec, const int* __restrict__ bincur,
                          u32* __restrict__ rp, int* __restrict__ col,
                          const float4* __restrict__ x, uint2* __restrict__ X1,
                          const float* __restrict__ Wrel1, const float* __restrict__ Wroot1,
                          const float* __restrict__ Wrel2, const float* __restrict__ Wroot2,
                          u16* __restrict__ wcat,
                          const float* __restrict__ W1, const float* __restrict__ W2,
                          u16* __restrict__ wm,
                          const int* __restrict__ batch, int* __restrict__ start){
  __shared__ u32 recs[MAXBIN];
  __shared__ int colL[MAXBIN];
  __shared__ int deg[BINSZ];
  __shared__ int cursor[BINSZ];
  __shared__ int sc[BINSZ];
  int blk = blockIdx.x, t = threadIdx.x;
  if (blk < C_BIN){
    int b = blk;
    int s0 = b*MAXBIN;
    int n = bincur[b];                 // bin-local count
    if (t < BINSZ) deg[t] = 0;
    for (int i = t; i < n; i += 256) recs[i] = rec[s0 + i];
    __syncthreads();
    for (int i = t; i < n; i += 256) atomicAdd(&deg[(recs[i] >> 16) & 127], 1);
    __syncthreads();
    if (t < BINSZ) sc[t] = deg[t];
    __syncthreads();
    for (int off = 1; off < BINSZ; off <<= 1){
      int u = 0;
      if (t < BINSZ && t >= off) u = sc[t - off];
      __syncthreads();
      if (t < BINSZ) sc[t] += u;
      __syncthreads();
    }
    if (t < BINSZ){
      int d = deg[t];
      int pref = sc[t] - d;
      cursor[t] = pref;
      int node = b*BINSZ + t;
      if (node < N_NODES) rp[node] = (u32)((s0 + pref) << 11) | (u32)min(d, 2047);
    }
    __syncthreads();
    for (int i = t; i < n; i += 256){
      u32 r = recs[i];
      int p = atomicAdd(&cursor[(r >> 16) & 127], 1);
      colL[p] = (int)(r & 0xFFFFu);
    }
    __syncthreads();
    for (int i = t; i < n; i += 256) col[s0 + i] = colL[i];
  } else if (blk < C_CAST){
    int i = (blk - C_BIN)*256 + t;             // exactly 1,600,000
    float4 v = x[i];
    X1[i] = make_uint2(pack2(v.x, v.y), pack2(v.z, v.w));
  } else if (blk < C_W2){
    int id = (blk - C_CAST)*256 + t;           // 65536
    int l = id >> 15;
    int r = id & 32767;
    int n = r >> 8;
    int k = r & 255;
    const float* Wrel  = l ? Wrel2  : Wrel1;
    const float* Wroot = l ? Wroot2 : Wroot1;
    float w = (k < 128) ? Wrel[k*128 + n] : Wroot[(k-128)*128 + n];
    int c = k >> 3, j = k & 7;
    wcat[l*32768 + n*256 + ((c ^ (n & 15)) << 3) + j] = f2b(w);
  } else if (blk < C_MLP){
    int id = (blk - C_W2)*256 + t;             // 32768
    int l = id >> 14;
    int r = id & 16383;
    int n = r >> 7;
    int k = r & 127;
    const float* W = l ? W2 : W1;
    wm[l*16384 + n*128 + k] = f2b(W[k*128 + n]);
  } else {
    int g = (blk - C_MLP)*256 + t;
    if (g <= N_GRAPHS){
      int lo = 0, hi = N_NODES;
      while (lo < hi){ int mid = (lo + hi) >> 1; if (batch[mid] < g) lo = mid + 1; else hi = mid; }
      start[g] = lo;
    }
  }
}

// ---- Aggregation: M[i] = (1/deg) * sum_{j in N(i)} X[j]  (bf16 out) --------
__global__ void k_aggm(const u16* __restrict__ X, const u32* __restrict__ rp,
                       const int* __restrict__ col, u16* __restrict__ M){
  int wave = threadIdx.x >> 6, lane = threadIdx.x & 63;
  int node = blockIdx.x*4 + wave;                 // grid covers exactly 50000
  int sub = lane >> 5, ln = lane & 31;
  const uint2* Xu = (const uint2*)X;
  int d;
  floatx4 a = gather_node(Xu, col, rp[node], lane, sub, ln, &d);
  if (sub == 0){
    float di = 1.0f / (float)max(d, 1);
    ((uint2*)M)[node*32 + ln] = make_uint2(pack2(a[0]*di, a[1]*di), pack2(a[2]*di, a[3]*di));
  }
}

// ---- GEMM: Xout = relu([M|X] @ Wcat + brel)  (M=50000, K=256, N=128) ------
__launch_bounds__(256, 2)
__global__ void k_gemm2(const u16* __restrict__ M, const u16* __restrict__ X,
                        const u16* __restrict__ Wcat, const float* __restrict__ brel,
                        u16* __restrict__ Xout){
  __shared__ u16 Bs[128*256];
  {
    const uint4* s = (const uint4*)Wcat;
    uint4* d = (uint4*)Bs;
    #pragma unroll
    for (int i = 0; i < 16; i++) d[threadIdx.x + 256*i] = s[threadIdx.x + 256*i];
  }
  __syncthreads();

  int wave = threadIdx.x >> 6, lane = threadIdx.x & 63;
  int l15 = lane & 15, quad = lane >> 4;
  int wy = wave >> 1, wx = wave & 1;
  int rowBase = blockIdx.x*128 + wy*64;

  floatx4 acc[4][4] = {};

  #pragma unroll
  for (int k0 = 0; k0 < 256; k0 += 32){
    const u16* Asrc = (k0 < 128) ? M : X;
    int kk = k0 & 127;
    int c = (k0 >> 3) + quad;
    short8 a[4];
    #pragma unroll
    for (int mt = 0; mt < 4; mt++){
      int row = rowBase + mt*16 + l15;
      if (row > N_NODES-1) row = N_NODES-1;   // clamp; stores are masked
      a[mt] = *(const short8*)(Asrc + row*128 + kk + quad*8);
    }
    #pragma unroll
    for (int nt = 0; nt < 4; nt++){
      int n = wx*64 + nt*16 + l15;
      short8 b = *(const short8*)(Bs + n*256 + ((c ^ (n & 15)) << 3));
      #pragma unroll
      for (int mt = 0; mt < 4; mt++)
        acc[mt][nt] = __builtin_amdgcn_mfma_f32_16x16x32_bf16(a[mt], b, acc[mt][nt], 0, 0, 0);
    }
  }

  float bc[4];
  #pragma unroll
  for (int nt = 0; nt < 4; nt++) bc[nt] = brel[wx*64 + nt*16 + l15];

  #pragma unroll
  for (int mt = 0; mt < 4; mt++){
    int rbase = rowBase + mt*16 + quad*4;
    #pragma unroll
    for (int r = 0; r < 4; r++){
      int row = rbase + r;
      if (row < N_NODES){
        #pragma unroll
        for (int nt = 0; nt < 4; nt++){
          int n = wx*64 + nt*16 + l15;
          Xout[row*128 + n] = f2b(fmaxf(acc[mt][nt][r] + bc[nt], 0.f));
        }
      }
    }
  }
}

// ---- fused agg3 + pool + conv3 ---------------------------------------------
__launch_bounds__(1024)
__global__ void k_aggpool(const u16* __restrict__ X3, const u32* __restrict__ rp,
                          const int* __restrict__ col, const int* __restrict__ start,
                          const float* __restrict__ Wrel, const float* __restrict__ Wroot,
                          const float* __restrict__ brel, u16* __restrict__ Gb){
  __shared__ float smM[16][128];
  __shared__ float smX[16][128];
  __shared__ float pmS[128], pxS[128], part[256];
  int g = blockIdx.x;
  int t = threadIdx.x, wave = t >> 6, lane = t & 63;
  int sub = lane >> 5, ln = lane & 31;
  int s = start[g], e = start[g+1];
  const uint2* Xu = (const uint2*)X3;

  float gm0=0.f, gm1=0.f, gm2=0.f, gm3=0.f;
  for (int i = s + wave; i < e; i += 16){
    int d;
    floatx4 a = gather_node(Xu, col, rp[i], lane, sub, ln, &d);
    float di = 1.0f / (float)max(d, 1);
    gm0 += a[0]*di; gm1 += a[1]*di; gm2 += a[2]*di; gm3 += a[3]*di;
  }
  float gx0=0.f, gx1=0.f, gx2=0.f, gx3=0.f;
  for (int i = s + wave*2 + sub; i < e; i += 32){
    uint2 v = Xu[i*32 + ln];
    gx0 += blo(v.x); gx1 += bhi(v.x); gx2 += blo(v.y); gx3 += bhi(v.y);
  }
  gx0 += __shfl_xor(gx0, 32); gx1 += __shfl_xor(gx1, 32);
  gx2 += __shfl_xor(gx2, 32); gx3 += __shfl_xor(gx3, 32);
  if (sub == 0){
    smM[wave][4*ln+0] = gm0; smM[wave][4*ln+1] = gm1;
    smM[wave][4*ln+2] = gm2; smM[wave][4*ln+3] = gm3;
    smX[wave][4*ln+0] = gx0; smX[wave][4*ln+1] = gx1;
    smX[wave][4*ln+2] = gx2; smX[wave][4*ln+3] = gx3;
  }
  __syncthreads();
  if (t < 128){
    float inv = 1.0f / (float)max(e - s, 1);
    float m = 0.f, xx = 0.f;
    #pragma unroll
    for (int w = 0; w < 16; w++){ m += smM[w][t]; xx += smX[w][t]; }
    pmS[t] = m*inv; pxS[t] = xx*inv;
  }
  __syncthreads();
  if (t < 256){
    int n = t & 127, half = t >> 7;
    const float* W = half ? Wroot : Wrel;
    const float* S = half ? pxS : pmS;
    float a = 0.f;
    for (int k = 0; k < 128; k++) a = fmaf(S[k], W[k*128 + n], a);
    part[t] = a;
  }
  __syncthreads();
  if (t < 128) Gb[g*128 + t] = f2b(part[t] + part[t + 128] + brel[t]);
}

// ---- fused MLP (8 blocks x 64 rows) ----------------------------------------
#define APAD 136
__launch_bounds__(256)
__global__ void k_mlp(const u16* __restrict__ Gb, const u16* __restrict__ wm,
                      const float* __restrict__ b1, const float* __restrict__ b2,
                      const float* __restrict__ Wo, const float* __restrict__ bo,
                      float* __restrict__ out){
  __shared__ u16 Apad[64*APAD];
  int t = threadIdx.x;
  int wave = t >> 6, lane = t & 63;
  int l15 = lane & 15, quad = lane >> 4;
  int R = blockIdx.x*64;

  floatx4 acc[8] = {};
  #pragma unroll
  for (int k0 = 0; k0 < 128; k0 += 32){
    int row = R + wave*16 + l15;
    short8 a = *(const short8*)(Gb + row*128 + k0 + quad*8);
    #pragma unroll
    for (int nt = 0; nt < 8; nt++){
      short8 b = *(const short8*)(wm + (nt*16 + l15)*128 + k0 + quad*8);
      acc[nt] = __builtin_amdgcn_mfma_f32_16x16x32_bf16(a, b, acc[nt], 0, 0, 0);
    }
  }
  #pragma unroll
  for (int nt = 0; nt < 8; nt++){
    int coln = nt*16 + l15;
    float bc = b1[coln];
    int lmb = wave*16 + quad*4;
    #pragma unroll
    for (int r = 0; r < 4; r++)
      Apad[(lmb + r)*APAD + coln] = f2b(fmaxf(acc[nt][r] + bc, 0.f));
  }
  __syncthreads();

  floatx4 acc2[8] = {};
  #pragma unroll
  for (int k0 = 0; k0 < 128; k0 += 32){
    short8 a = *(const short8*)(Apad + (wave*16 + l15)*APAD + k0 + quad*8);
    #pragma unroll
    for (int nt = 0; nt < 8; nt++){
      short8 b = *(const short8*)(wm + 16384 + (nt*16 + l15)*128 + k0 + quad*8);
      acc2[nt] = __builtin_amdgcn_mfma_f32_16x16x32_bf16(a, b, acc2[nt], 0, 0, 0);
    }
  }
  __syncthreads();
  #pragma unroll
  for (int nt = 0; nt < 8; nt++){
    int coln = nt*16 + l15;
    float bc = b2[coln];
    int lmb = wave*16 + quad*4;
    #pragma unroll
    for (int r = 0; r < 4; r++)
      Apad[(lmb + r)*APAD + coln] = f2b(fmaxf(acc2[nt][r] + bc, 0.f));
  }
  __syncthreads();

  if (t < 128){
    int row = t >> 1;
    int c0  = (t & 1)*4;
    float o0 = bo[c0], o1 = bo[c0+1], o2 = bo[c0+2], o3 = bo[c0+3];
    for (int k = 0; k < 128; k++){
      float h = b2f(Apad[row*APAD + k]);
      const float* w = Wo + k*8 + c0;
      o0 = fmaf(h, w[0], o0); o1 = fmaf(h, w[1], o1);
      o2 = fmaf(h, w[2], o2); o3 = fmaf(h, w[3], o3);
    }
    float* op = out + (R + row)*8 + c0;
    op[0] = o0; op[1] = o1; op[2] = o2; op[3] = o3;
  }
}

extern "C" void kernel_launch(void* const* d_in, const int* in_sizes, int n_in,
                              void* d_out, int out_size, void* d_ws, size_t ws_size,
                              hipStream_t stream){
  const float* x     = (const float*)d_in[0];
  const int*   ei    = (const int*)d_in[1];
  const int*   batch = (const int*)d_in[2];
  const float* Wrel1 = (const float*)d_in[3];
  const float* brel1 = (const float*)d_in[4];
  const float* Wroot1= (const float*)d_in[5];
  const float* Wrel2 = (const float*)d_in[6];
  const float* brel2 = (const float*)d_in[7];
  const float* Wroot2= (const float*)d_in[8];
  const float* Wrel3 = (const float*)d_in[9];
  const float* brel3 = (const float*)d_in[10];
  const float* Wroot3= (const float*)d_in[11];
  const float* W1 = (const float*)d_in[12]; const float* b1 = (const float*)d_in[13];
  const float* W2 = (const float*)d_in[14]; const float* b2 = (const float*)d_in[15];
  const float* Wo = (const float*)d_in[16]; const float* bo = (const float*)d_in[17];
  const int* esrc = ei;
  const int* edst = ei + N_EDGES;

  char* ws = (char*)d_ws;
  size_t off = 0;
  auto alloc = [&](size_t bytes)->char*{
    char* p = ws + off; off += (bytes + 255) & ~(size_t)255; return p;
  };
  u16*   X1     = (u16*)  alloc((size_t)N_NODES*128*2);
  u16*   X2     = (u16*)  alloc((size_t)N_NODES*128*2);
  u16*   X3     = (u16*)  alloc((size_t)N_NODES*128*2);
  u16*   Mb     = (u16*)  alloc((size_t)N_NODES*128*2);
  u16*   wcat   = (u16*)  alloc((size_t)2*128*256*2);
  u16*   wm     = (u16*)  alloc((size_t)2*128*128*2);
  u16*   Gb     = (u16*)  alloc((size_t)N_GRAPHS*128*2);
  u32*   rp     = (u32*)  alloc((size_t)N_NODES*4);
  int*   colIdx = (int*)  alloc((size_t)NBIN*MAXBIN*4);   // doubles as rec buffer
  int*   start  = (int*)  alloc((size_t)(N_GRAPHS+1)*4);
  int*   bincur = (int*)  alloc((size_t)NBIN*4);
  u32*   rec    = (u32*)colIdx;

  dim3 b256(256);
  hipMemsetAsync(bincur, 0, (size_t)NBIN*4, stream);
  k_scatter<<<NSCAT, dim3(1024), 0, stream>>>(esrc, edst, bincur, rec);
  k_csrprep<<<C_BND, b256, 0, stream>>>(rec, bincur, rp, colIdx,
                                        (const float4*)x, (uint2*)X1,
                                        Wrel1, Wroot1, Wrel2, Wroot2, wcat,
                                        W1, W2, wm, batch, start);

  const int ggrid = (N_NODES + 127)/128;   // 391
  const int agrid = N_NODES/4;             // 12500

  k_aggm <<<agrid, b256, 0, stream>>>(X1, rp, colIdx, Mb);
  k_gemm2<<<ggrid, b256, 0, stream>>>(Mb, X1, wcat + 0*32768, brel1, X2);

  k_aggm <<<agrid, b256, 0, stream>>>(X2, rp, colIdx, Mb);
  k_gemm2<<<ggrid, b256, 0, stream>>>(Mb, X2, wcat + 1*32768, brel2, X3);

  k_aggpool<<<N_GRAPHS, dim3(1024), 0, stream>>>(X3, rp, colIdx, start,
                                                 Wrel3, Wroot3, brel3, Gb);
  k_mlp    <<<8, b256, 0, stream>>>(Gb, wm, b1, b2, Wo, bo, (float*)d_out);
}